// Round 8
// baseline (4312.446 us; speedup 1.0000x reference)
//
#include <hip/hip_runtime.h>

// ---------------------------------------------------------------------------
// RNN_Layer: x[B,T,C] fp32 -> conv1x1(w_in) -> dense(kernel) -> LSTM(rec)
//            -> dense(w_out).  B=32 T=1024 C=512 D=256 U=256 O=256.
// R14: barrier-free wave pipeline on top of R13 (1534us LSTM, MfmaUtil-act
// ~57%).  R13's gap to the 2480cyc/SIMD MFMA floor was the SYNCHRONIZED step
// tail: the per-step barrier made all 8 waves do gates+h-write+A-read-latency
// with the matrix pipe idle.  Key fact: A-frag for k-chunk kc = h[32kc..+31]
// = produced by wave kc.  So: rotated kc order (w, w+1, ..) per wave -- own
// slice first (no wait), each other slice gated on LDS flag[kc] >= t.
//   producer: h ds_write -> lgkmcnt(0) -> flag[w]=t+1 (volatile LDS)
//   consumer: spin flag[kcn]>=t (steady-state: already set) -> lgkmcnt(0)
//             fence (asm, "memory") -> A-frag ds_read.
// Protocol audit: writes of h_{t+1} happen only after all flags>=t (every
// wave done READING h_{t-1}, same parity buffer) -> no alias; skew < 2 steps;
// monotonic flags -> no deadlock.  Rule-#20 avoided: resident strips are
// PACKED in rotated order at load time (reg arrays compile-time indexed).
// Rest identical to R13: broadcast-A, 4 strips "+a" (128 AGPR) + 2 "+v",
// o-strips streamed from 128 KiB LDS, gates in-lane (q<2), h parity dbuf.
// ---------------------------------------------------------------------------

#define DEV static __device__ __forceinline__

typedef __attribute__((ext_vector_type(8))) short short8;
typedef __attribute__((ext_vector_type(4))) float floatx4;
typedef _Float16 half8 __attribute__((ext_vector_type(8)));

static constexpr int Bsz = 32, T = 1024, C = 512, D = 256, U = 256, FU = 1024;
static constexpr int M = Bsz * T;   // 32768 rows for all GEMMs

DEV float bfu2f(unsigned int u) { union { unsigned int i; float f; } v; v.i = u; return v.f; }
DEV float bf2f(unsigned short u) { return bfu2f(((unsigned int)u) << 16); }
DEV unsigned short f2bf(float f) {
    union { float f; unsigned int i; } v; v.f = f;
    return (unsigned short)((v.i + 0x7fffu + ((v.i >> 16) & 1u)) >> 16);
}
DEV float sigmf(float x) { return 1.0f / (1.0f + __expf(-x)); }
DEV float tanhfast(float x) {
    const float a = __expf(-2.0f * fabsf(x));
    const float t = (1.0f - a) / (1.0f + a);
    return copysignf(t, x);
}
DEV half8 h8c(uint4 v) { return __builtin_bit_cast(half8, v); }

// fp32-or-bf16 element -> bf16 bit pattern (GEMM operand loads)
DEV short ld_bf(const float* p) { return (short)f2bf(*p); }
DEV short ld_bf(const unsigned short* p) { return (short)*p; }
DEV short8 ld_frag(const unsigned short* p) { return *(const short8*)p; }
DEV short8 ld_frag(const float* p) {
    short8 v;
#pragma unroll
    for (int j = 0; j < 8; j++) v[j] = (short)f2bf(p[j]);
    return v;
}
DEV float ldxz1(const float* p) { return *p; }
DEV float ldxz1(const unsigned short* p) { return bf2f(*p); }

// LDS-only wait with compiler memory barrier (orders ds ops; does NOT drain
// vmcnt, so xz prefetch / hs stores stay in flight).
#define LGKM0() asm volatile("s_waitcnt lgkmcnt(0)" ::: "memory")

// ---------------------------------------------------------------------------
// Fragment-direct MFMA GEMM:  C[M,N] = A[M,K] @ B[K,N] + bias[N]
// Layouts (m89/m120-verified): A[m=lane&15][k=quad*8+j];
//   B[k=quad*8+j][n=lane&15]; D[m=quad*4+r][n=lane&15]
// ---------------------------------------------------------------------------
template <int K, int N, int MT, int NS, bool OUTF32, typename AT, typename BT>
__global__ __launch_bounds__(64) void gemm_mfma(
    const AT* __restrict__ A,
    const BT* __restrict__ Bm,
    const float* __restrict__ bias,
    void* __restrict__ Cv)
{
    constexpr int KC = K / 32;
    const int lane = threadIdx.x;
    const int quad = lane >> 4, lr = lane & 15;
    constexpr int NSG = N / (16 * NS);
    const int sg = blockIdx.x % NSG;
    const int mb = blockIdx.x / NSG;
    const int n0 = sg * 16 * NS;

    short8 bf[NS][KC];
    float biasv[NS];
#pragma unroll
    for (int s = 0; s < NS; s++) {
        const int n = n0 + s * 16 + lr;
        biasv[s] = bias[n];
#pragma unroll
        for (int kc = 0; kc < KC; kc++) {
            short8 v;
#pragma unroll
            for (int j = 0; j < 8; j++) {
                const int k = kc * 32 + quad * 8 + j;
                v[j] = ld_bf(&Bm[(size_t)k * N + n]);
            }
            bf[s][kc] = v;
        }
    }

    for (int mt = 0; mt < MT; mt++) {
        const int m0 = (mb * MT + mt) * 16;
        const AT* Ap = A + (size_t)(m0 + lr) * K + quad * 8;
        floatx4 acc[NS];
#pragma unroll
        for (int s = 0; s < NS; s++) acc[s] = (floatx4){0.f, 0.f, 0.f, 0.f};
#pragma unroll
        for (int kc = 0; kc < KC; kc++) {
            short8 af = ld_frag(Ap + kc * 32);
#pragma unroll
            for (int s = 0; s < NS; s++)
                acc[s] = __builtin_amdgcn_mfma_f32_16x16x32_bf16(af, bf[s][kc], acc[s], 0, 0, 0);
        }
#pragma unroll
        for (int s = 0; s < NS; s++) {
            const int n = n0 + s * 16 + lr;
#pragma unroll
            for (int r = 0; r < 4; r++) {
                const int m = m0 + quad * 4 + r;
                const float val = acc[s][r] + biasv[s];
                if (OUTF32)
                    ((float*)Cv)[(size_t)m * N + n] = val;
                else
                    ((unsigned short*)Cv)[(size_t)m * N + n] = f2bf(val);
            }
        }
    }
}

// ---------------------------------------------------------------------------
// Pack rec_kernel fp32 [256][1024] -> f16 MFMA B-fragments, 64 strips
// (R7-verified).  Pm[(strip*8+kc)*64+lane].j =
//   f16( rec[kc*32+(lane>>4)*8+j][strip*16+(lane&15)] )
// ---------------------------------------------------------------------------
__global__ __launch_bounds__(256) void pack_rec_mfma(const float* __restrict__ rec,
                                                     uint4* __restrict__ Pm)
{
    const int idx = blockIdx.x * 256 + threadIdx.x;   // 0..32767
    const int lane = idx & 63;
    const int kc = (idx >> 6) & 7;
    const int strip = idx >> 9;
    const int q = lane >> 4, lr = lane & 15;
    const int col = strip * 16 + lr;
    const int k0 = kc * 32 + q * 8;
    union { unsigned short u[8]; uint4 v; } out;
#pragma unroll
    for (int j = 0; j < 8; j++) {
        const _Float16 h = (_Float16)rec[(size_t)(k0 + j) * FU + col];
        out.u[j] = __builtin_bit_cast(unsigned short, h);
    }
    Pm[idx] = out.v;
}

// ---------------------------------------------------------------------------
// Barrier-free broadcast-A MFMA LSTM.  1 WG (512 thr / 8 waves, 2/SIMD) per
// batch.  Wave w: strips 2w,2w+1(i) 16/17+2w(f) 32/33+2w(g) resident
// (rotated kc packing), 48/49+2w(o) streamed from LDS.  Per-wave flags
// replace the step barrier; kc processed in order (w, w+1, ...).
// ---------------------------------------------------------------------------
template <typename XZT>
__global__ __launch_bounds__(512, 2)
void lstm_flow(
    const XZT* __restrict__ xz,            // [B, T, 4U]
    const uint4* __restrict__ Pm,          // packed rec frags, 64 strips
    unsigned short* __restrict__ hs)       // [B, T, U] bf16 out
{
    const int b = blockIdx.x;
    const int tid = threadIdx.x;
    const int w = tid >> 6;                // wave 0..7
    const int lane = tid & 63;
    const int q = lane >> 4, lr = lane & 15;

    __shared__ uint4 Wl[16 * 8 * 64];                    // o-strips: 128 KiB
    __shared__ __align__(16) unsigned short h_pk[2][U];  // h f16 dbuf: 1 KiB
    __shared__ volatile unsigned int flags[8];           // per-wave step count

    // stage o-strips: slot sl (0..15) <- global strip 48 + 2*(sl>>1) + (sl&1)
    for (int i = tid; i < 16 * 8 * 64; i += 512) {
        const int sl = i >> 9;
        const int gs = 48 + 2 * (sl >> 1) + (sl & 1);
        Wl[i] = Pm[(size_t)gs * 512 + (i & 511)];
    }
    if (tid < 128) { ((unsigned int*)h_pk[0])[tid] = 0; }
    if (tid < 8) flags[tid] = 0u;

    // resident strips, packed in ROTATED kc order: slot j holds kc=(w+j)&7
    // (rule #20: register arrays must be compile-time indexed; the rotation
    //  lives in the global-load address instead).
    uint4 Wa0[8], Wa1[8], Wa2[8], Wa3[8];   // -> AGPR (128)
    uint4 Wv0[8], Wv1[8];                   // -> arch VGPR (64)
#pragma unroll
    for (int j = 0; j < 8; j++) {
        const int kc = (w + j) & 7;
        Wa0[j] = Pm[((size_t)(2 * w + 0) * 8 + kc) * 64 + lane];    // i even
        Wa1[j] = Pm[((size_t)(2 * w + 1) * 8 + kc) * 64 + lane];    // i odd
        Wa2[j] = Pm[((size_t)(16 + 2 * w) * 8 + kc) * 64 + lane];   // f even
        Wa3[j] = Pm[((size_t)(17 + 2 * w) * 8 + kc) * 64 + lane];   // f odd
        Wv0[j] = Pm[((size_t)(32 + 2 * w) * 8 + kc) * 64 + lane];   // g even
        Wv1[j] = Pm[((size_t)(33 + 2 * w) * 8 + kc) * 64 + lane];   // g odd
    }
    // Pin: 4 strips to AGPRs (MFMA reads B from AGPR natively), 2 to arch
    // VGPRs.  128a + 64v + acc/A/misc fits the 256 unified regs/wave.
#pragma unroll
    for (int j = 0; j < 8; j++) {
        asm volatile("" : "+a"(Wa0[j].x), "+a"(Wa0[j].y), "+a"(Wa0[j].z), "+a"(Wa0[j].w));
        asm volatile("" : "+a"(Wa1[j].x), "+a"(Wa1[j].y), "+a"(Wa1[j].z), "+a"(Wa1[j].w));
        asm volatile("" : "+a"(Wa2[j].x), "+a"(Wa2[j].y), "+a"(Wa2[j].z), "+a"(Wa2[j].w));
        asm volatile("" : "+a"(Wa3[j].x), "+a"(Wa3[j].y), "+a"(Wa3[j].z), "+a"(Wa3[j].w));
        asm volatile("" : "+v"(Wv0[j].x), "+v"(Wv0[j].y), "+v"(Wv0[j].z), "+v"(Wv0[j].w));
        asm volatile("" : "+v"(Wv1[j].x), "+v"(Wv1[j].y), "+v"(Wv1[j].z), "+v"(Wv1[j].w));
    }
    __syncthreads();   // staging + flag init visible to all waves (once)

    const XZT* xzb = xz + (size_t)b * T * FU;
    unsigned short* hsb = hs + (size_t)b * T * U;

    // gate-phase ownership: lanes q<2 own unit u = 32w + 16q + lr
    const int u = 32 * w + 16 * q + lr;
    const bool gact = (q < 2);

    float cst = 0.f;
    float xzi = 0.f, xzf = 0.f, xzg = 0.f, xzo = 0.f;
    if (gact) {
        xzi = ldxz1(xzb + u);        xzf = ldxz1(xzb + 256 + u);
        xzg = ldxz1(xzb + 512 + u);  xzo = ldxz1(xzb + 768 + u);
    }

    for (int t = 0; t < T; t++) {
        // prefetch next xz (vmcnt stays untouched by LGKM0 waits)
        float xzi_n = 0.f, xzf_n = 0.f, xzg_n = 0.f, xzo_n = 0.f;
        if (gact && t + 1 < T) {
            const XZT* xt = xzb + (size_t)(t + 1) * FU;
            xzi_n = ldxz1(xt + u);       xzf_n = ldxz1(xt + 256 + u);
            xzg_n = ldxz1(xt + 512 + u); xzo_n = ldxz1(xt + 768 + u);
        }

        const char* hb = ((const char*)h_pk) + (t & 1) * 512;

        floatx4 a0 = {0.f,0.f,0.f,0.f}, a1 = {0.f,0.f,0.f,0.f};
        floatx4 a2 = {0.f,0.f,0.f,0.f}, a3 = {0.f,0.f,0.f,0.f};
        floatx4 a4 = {0.f,0.f,0.f,0.f}, a5 = {0.f,0.f,0.f,0.f};
        floatx4 a6 = {0.f,0.f,0.f,0.f}, a7 = {0.f,0.f,0.f,0.f};

        // j=0: kc = w = OWN h slice (written by this wave last step; same-wave
        // ds ordering + the pre-flag LGKM0 of step t-1 make it safe, no wait).
        uint4 afc = *(const uint4*)(hb + w * 64 + q * 16), afn;

#pragma unroll
        for (int j = 0; j < 8; j++) {
            const int kc = (w + j) & 7;
            if (j < 7) {
                const int kcn = (w + j + 1) & 7;
                // gate on producer wave kcn having published h_t
                while (flags[kcn] < (unsigned int)t) { }
                LGKM0();   // acquire: flag read retired -> h writes visible
                afn = *(const uint4*)(hb + kcn * 64 + q * 16);
            }
            const uint4 s6 = Wl[((w * 2 + 0) * 8 + kc) * 64 + lane];
            const uint4 s7 = Wl[((w * 2 + 1) * 8 + kc) * 64 + lane];
            const half8 av = h8c(afc);
            a0 = __builtin_amdgcn_mfma_f32_16x16x32_f16(av, h8c(Wa0[j]), a0, 0, 0, 0);
            a1 = __builtin_amdgcn_mfma_f32_16x16x32_f16(av, h8c(Wa1[j]), a1, 0, 0, 0);
            a2 = __builtin_amdgcn_mfma_f32_16x16x32_f16(av, h8c(Wa2[j]), a2, 0, 0, 0);
            a3 = __builtin_amdgcn_mfma_f32_16x16x32_f16(av, h8c(Wa3[j]), a3, 0, 0, 0);
            a4 = __builtin_amdgcn_mfma_f32_16x16x32_f16(av, h8c(Wv0[j]), a4, 0, 0, 0);
            a5 = __builtin_amdgcn_mfma_f32_16x16x32_f16(av, h8c(Wv1[j]), a5, 0, 0, 0);
            a6 = __builtin_amdgcn_mfma_f32_16x16x32_f16(av, h8c(s6), a6, 0, 0, 0);
            a7 = __builtin_amdgcn_mfma_f32_16x16x32_f16(av, h8c(s7), a7, 0, 0, 0);
            afc = afn;
        }

        // gates: every D row equals z -> acc*[0] is z for col lr in EVERY
        // lane.  q==0 -> even strips (unit 32w+lr), q==1 -> odd (32w+16+lr).
        if (gact) {
            float zi_, zf_, zg_, zo_;
            if (q == 0) { zi_ = a0[0]; zf_ = a2[0]; zg_ = a4[0]; zo_ = a6[0]; }
            else        { zi_ = a1[0]; zf_ = a3[0]; zg_ = a5[0]; zo_ = a7[0]; }
            const float iv = sigmf(zi_ + xzi);
            const float fv = sigmf(zf_ + xzf);
            const float gv = tanhfast(zg_ + xzg);
            const float ov = sigmf(zo_ + xzo);
            cst = fv * cst + iv * gv;
            const float hv = ov * tanhfast(cst);
            h_pk[(t + 1) & 1][u] = __builtin_bit_cast(unsigned short, (_Float16)hv);
            hsb[(size_t)t * U + u] = f2bf(hv);
        }
        // release: h writes retired to LDS, then publish the step count
        LGKM0();
        if (lane == 0) flags[w] = (unsigned int)(t + 1);

        xzi = xzi_n; xzf = xzf_n; xzg = xzg_n; xzo = xzo_n;
    }
}

// ---------------------------------------------------------------------------
extern "C" void kernel_launch(void* const* d_in, const int* in_sizes, int n_in,
                              void* d_out, int out_size, void* d_ws, size_t ws_size,
                              hipStream_t stream)
{
    const float* x    = (const float*)d_in[0];
    const float* w_in = (const float*)d_in[1];
    const float* b_in = (const float*)d_in[2];
    const float* kern = (const float*)d_in[3];
    const float* rec  = (const float*)d_in[4];
    const float* bias = (const float*)d_in[5];
    const float* wout = (const float*)d_in[6];
    const float* bout = (const float*)d_in[7];

    char* ws = (char*)d_ws;
    const size_t rec_bytes = (size_t)64 * 8 * 64 * 16;    // 512 KiB packed W frags
    const size_t xin_bytes = (size_t)M * D * 2;           // 16 MiB
    const size_t hs_bytes  = (size_t)M * U * 2;           // 16 MiB
    const size_t xz32_bytes = (size_t)M * FU * 4;         // 128 MiB
    const size_t base = rec_bytes + xin_bytes + hs_bytes;

    uint4* Pm = (uint4*)ws;
    unsigned short* xin_bf = (unsigned short*)(ws + rec_bytes);
    unsigned short* hs_bf  = (unsigned short*)(ws + rec_bytes + xin_bytes);
    char* xz_raw = ws + base;

    const bool use_f32 = ws_size >= base + xz32_bytes;

    // pack rec_kernel -> f16 MFMA fragment layout (every launch; ws re-poisoned)
    pack_rec_mfma<<<128, 256, 0, stream>>>(rec, Pm);

    // GEMM1: xin = bf16(x @ w_in + b_in)   [M,512]x[512,256]
    gemm_mfma<512, 256, 16, 2, false><<<(256 / 32) * (M / 256), 64, 0, stream>>>(
        x, w_in, b_in, (void*)xin_bf);

    if (use_f32) {
        float* xzp = (float*)xz_raw;
        // GEMM2: xz = fp32(xin @ kernel + bias)  [M,256]x[256,1024]
        gemm_mfma<256, 1024, 16, 2, true><<<(1024 / 32) * (M / 256), 64, 0, stream>>>(
            xin_bf, kern, bias, (void*)xzp);
        lstm_flow<float><<<Bsz, 512, 0, stream>>>(xzp, Pm, hs_bf);
    } else {
        unsigned short* xzp = (unsigned short*)xz_raw;
        gemm_mfma<256, 1024, 16, 2, false><<<(1024 / 32) * (M / 256), 64, 0, stream>>>(
            xin_bf, kern, bias, (void*)xzp);
        lstm_flow<unsigned short><<<Bsz, 512, 0, stream>>>(xzp, Pm, hs_bf);
    }

    // GEMM3: out = fp32(hs @ w_out + b_out)  [M,256]x[256,256]
    gemm_mfma<256, 256, 16, 2, true><<<(256 / 32) * (M / 256), 64, 0, stream>>>(
        hs_bf, wout, bout, d_out);
}